// Round 4
// baseline (773.871 us; speedup 1.0000x reference)
//
#include <hip/hip_runtime.h>
#include <hip/hip_bf16.h>

// EulerIntegrator: B=4096, D=1024, R=256, steps=8, dt=0.01
// Round 4: 128 blocks x 32 rows x 1024 threads (16 waves).
//  - Halves the structural L2 B-stream: 128 blk x 8 MB = 1 GB (floor ~30 us).
//  - Peak live VGPRs kept < 128 BY CONSTRUCTION (allocator empirically pins
//    128 regardless of launch_bounds): GEMM2 chunked into 2 x 4 tiles
//    (acc=16), force carried bf16 in LDS, rings never overlap live accs.
//  - lgkm-only barriers + cross-phase prefetch rings kept from round 2/3.
//  - nontemporal for streaming edges (x0/v0/force/out) to protect the 1 MB
//    Up/Wp working set in per-XCD L2.

#define BB 4096
#define DD 1024
#define RR 256
#define DT 0.01f
#define ROWS 32

typedef __attribute__((ext_vector_type(8))) short short8;   // 8 bf16 = 4 VGPRs
typedef __attribute__((ext_vector_type(4))) float floatx4;  // MFMA acc

// s_waitcnt imm: vmcnt[3:0]|[15:14], expcnt[6:4], lgkmcnt[11:8]
// lgkmcnt(0) only; in-flight global loads survive the barrier.
#define BARRIER_LGKM() do { \
    __builtin_amdgcn_s_waitcnt(0xC07F); \
    __builtin_amdgcn_s_barrier(); \
} while (0)

static __device__ inline unsigned short f2bf(float f) {
    union { float f; unsigned int u; } c; c.f = f;
    unsigned int u = c.u;
    u += 0x7fffu + ((u >> 16) & 1u);   // round-to-nearest-even
    return (unsigned short)(u >> 16);
}
static __device__ inline float bf2f(unsigned short u) {
    union { unsigned int u; float f; } c; c.u = ((unsigned int)u) << 16;
    return c.f;
}

// Pack U [1024][256] and W [256][1024] (fp32 row-major) into bf16 MFMA
// B-fragment order: dst[(kt*NT + nt)*64 + lane] = 8 bf16, element j =
// M[kt*32 + (lane>>4)*8 + j][nt*16 + (lane&15)].
__global__ void pack_kernel(const float* __restrict__ U, const float* __restrict__ W,
                            short* __restrict__ Up, short* __restrict__ Wp) {
    int t = blockIdx.x * blockDim.x + threadIdx.x;  // 0..65535
    if (t < 32768) {
        int lane = t & 63;
        int nl = lane & 15, kq = lane >> 4;
        int idx = t >> 6;            // kt*16 + nt
        int nt = idx & 15, kt = idx >> 4;
        short8 o;
#pragma unroll
        for (int j = 0; j < 8; j++) {
            int k = kt * 32 + kq * 8 + j;
            int n = nt * 16 + nl;
            o[j] = (short)f2bf(U[k * RR + n]);
        }
        ((short8*)Up)[t] = o;
    } else {
        int t2 = t - 32768;
        int lane = t2 & 63;
        int nl = lane & 15, kq = lane >> 4;
        int idx = t2 >> 6;           // kt*64 + nt
        int nt = idx & 63, kt = idx >> 6;
        short8 o;
#pragma unroll
        for (int j = 0; j < 8; j++) {
            int k = kt * 32 + kq * 8 + j;
            int n = nt * 16 + nl;
            o[j] = (short)f2bf(W[k * DD + n]);
        }
        ((short8*)Wp)[t2] = o;
    }
}

__global__ __launch_bounds__(1024, 4)
void euler_kernel(const float* __restrict__ x0,
                  const float* __restrict__ v0,
                  const float* __restrict__ force,
                  const short8* __restrict__ Up,
                  const short8* __restrict__ Wp,
                  const int* __restrict__ steps_p,
                  float* __restrict__ out) {
    __shared__ __align__(16) short v_lds[ROWS][1032];   // 66.0 KB bf16 v
    __shared__ __align__(16) short f_lds[ROWS][1032];   // 66.0 KB bf16 force
    __shared__ __align__(16) short p2_lds[ROWS][264];   // 16.9 KB bf16 p^2
                                                        // total 149 KB (<160)

    const int tid  = threadIdx.x;
    const int wave = tid >> 6;          // 0..15
    const int lane = tid & 63;
    const int nl   = lane & 15;
    const int quad = lane >> 4;
    const int mt   = wave >> 3;         // 0,1 : which 16-row half
    const int wg   = wave & 7;          // 0..7 : N-group
    const int row0 = blockIdx.x * ROWS;

    const int steps = steps_p[0];

    // Ownership (GEMM2 C/D layout): (tt 0..7, r 0..3):
    //   row = 16*mt + 4*quad + r, col = 128*wg + 16*tt + nl
    float v_reg[8][4], sv[8][4];

#pragma unroll
    for (int tt = 0; tt < 8; tt++) {
        int col = 128 * wg + 16 * tt + nl;
#pragma unroll
        for (int r = 0; r < 4; r++) {
            int row = 16 * mt + 4 * quad + r;
            long g = (long)(row0 + row) * DD + col;
            float vv = __builtin_nontemporal_load(&v0[g]);
            float ff = __builtin_nontemporal_load(&force[g]);
            v_reg[tt][r] = vv;
            sv[tt][r] = 0.0f;
            v_lds[row][col] = (short)f2bf(vv);
            f_lds[row][col] = (short)f2bf(ff);
        }
    }

    // GEMM1 B-ring, depth 4 (32 regs). U n-tiles: wave handles 2*wg, 2*wg+1.
    short8 b0r[4], b1r[4];
#pragma unroll
    for (int i = 0; i < 4; i++) {
        b0r[i] = Up[(i * 16 + 2 * wg    ) * 64 + lane];
        b1r[i] = Up[(i * 16 + 2 * wg + 1) * 64 + lane];
    }

    BARRIER_LGKM();

    for (int s = 0; s < steps; s++) {
        // ---------------- GEMM1: P[32x256] = v @ U
        floatx4 acc0 = {0.f, 0.f, 0.f, 0.f};
        floatx4 acc1 = {0.f, 0.f, 0.f, 0.f};
#pragma unroll
        for (int kt = 0; kt < 32; kt++) {
            short8 a = *(const short8*)&v_lds[16 * mt + nl][kt * 32 + quad * 8];
            acc0 = __builtin_amdgcn_mfma_f32_16x16x32_bf16(a, b0r[kt & 3], acc0, 0, 0, 0);
            acc1 = __builtin_amdgcn_mfma_f32_16x16x32_bf16(a, b1r[kt & 3], acc1, 0, 0, 0);
            if (kt < 28) {
                b0r[kt & 3] = Up[((kt + 4) * 16 + 2 * wg    ) * 64 + lane];
                b1r[kt & 3] = Up[((kt + 4) * 16 + 2 * wg + 1) * 64 + lane];
            }
        }

        // GEMM2 chunk-A prologue (kt=0, tt=0..3) — crosses the p2 barrier.
        short8 brA[4];
#pragma unroll
        for (int j = 0; j < 4; j++)
            brA[j] = Wp[(8 * wg + j) * 64 + lane];

        // p^2 epilogue -> LDS
#pragma unroll
        for (int r = 0; r < 4; r++) {
            int prow = 16 * mt + 4 * quad + r;
            float p0 = acc0[r], p1 = acc1[r];
            p2_lds[prow][32 * wg + nl]      = (short)f2bf(p0 * p0);
            p2_lds[prow][32 * wg + 16 + nl] = (short)f2bf(p1 * p1);
        }
        BARRIER_LGKM();

        // ---------------- GEMM2 chunk A: G tiles tt=0..3 (acc = 16 regs)
        floatx4 acc[4];
#pragma unroll
        for (int j = 0; j < 4; j++) acc[j] = (floatx4){0.f, 0.f, 0.f, 0.f};
        short8 a2;
#pragma unroll
        for (int f = 0; f < 32; f++) {
            int kt = f >> 2, j = f & 3;
            if (j == 0)
                a2 = *(const short8*)&p2_lds[16 * mt + nl][kt * 32 + quad * 8];
            acc[j] = __builtin_amdgcn_mfma_f32_16x16x32_bf16(a2, brA[j], acc[j], 0, 0, 0);
            if (f < 28)
                brA[j] = Wp[((kt + 1) * 64 + 8 * wg + j) * 64 + lane];
        }

        // chunk-B prologue — latency hidden by epilogue-A VALU.
        short8 brB[4];
#pragma unroll
        for (int j = 0; j < 4; j++)
            brB[j] = Wp[(8 * wg + 4 + j) * 64 + lane];

        // epilogue A: Euler update for tt=0..3
#pragma unroll
        for (int j = 0; j < 4; j++) {
            int col = 128 * wg + 16 * j + nl;
#pragma unroll
            for (int r = 0; r < 4; r++) {
                int row = 16 * mt + 4 * quad + r;
                float fv = bf2f((unsigned short)f_lds[row][col]);
                sv[j][r] += v_reg[j][r];
                v_reg[j][r] += DT * (fv - acc[j][r]);
                v_lds[row][col] = (short)f2bf(v_reg[j][r]);
            }
        }

        // ---------------- GEMM2 chunk B: G tiles tt=4..7
#pragma unroll
        for (int j = 0; j < 4; j++) acc[j] = (floatx4){0.f, 0.f, 0.f, 0.f};
#pragma unroll
        for (int f = 0; f < 32; f++) {
            int kt = f >> 2, j = f & 3;
            if (j == 0)
                a2 = *(const short8*)&p2_lds[16 * mt + nl][kt * 32 + quad * 8];
            acc[j] = __builtin_amdgcn_mfma_f32_16x16x32_bf16(a2, brB[j], acc[j], 0, 0, 0);
            if (f < 28)
                brB[j] = Wp[((kt + 1) * 64 + 8 * wg + 4 + j) * 64 + lane];
        }

        // next-step GEMM1 prologue — crosses the end-of-step barrier.
#pragma unroll
        for (int i = 0; i < 4; i++) {
            b0r[i] = Up[(i * 16 + 2 * wg    ) * 64 + lane];
            b1r[i] = Up[(i * 16 + 2 * wg + 1) * 64 + lane];
        }

        // epilogue B: Euler update for tt=4..7
#pragma unroll
        for (int j = 0; j < 4; j++) {
            int tt = 4 + j;
            int col = 128 * wg + 16 * tt + nl;
#pragma unroll
            for (int r = 0; r < 4; r++) {
                int row = 16 * mt + 4 * quad + r;
                float fv = bf2f((unsigned short)f_lds[row][col]);
                sv[tt][r] += v_reg[tt][r];
                v_reg[tt][r] += DT * (fv - acc[j][r]);
                v_lds[row][col] = (short)f2bf(v_reg[tt][r]);
            }
        }
        BARRIER_LGKM();
    }

    // outputs: [cx | cv], cx = x0 + dt * sum(v_t)
#pragma unroll
    for (int tt = 0; tt < 8; tt++) {
        int col = 128 * wg + 16 * tt + nl;
#pragma unroll
        for (int r = 0; r < 4; r++) {
            int row = 16 * mt + 4 * quad + r;
            long g = (long)(row0 + row) * DD + col;
            float xx = __builtin_nontemporal_load(&x0[g]);
            __builtin_nontemporal_store(xx + DT * sv[tt][r], &out[g]);
            __builtin_nontemporal_store(v_reg[tt][r], &out[(long)BB * DD + g]);
        }
    }
}

extern "C" void kernel_launch(void* const* d_in, const int* in_sizes, int n_in,
                              void* d_out, int out_size, void* d_ws, size_t ws_size,
                              hipStream_t stream) {
    const float* x     = (const float*)d_in[0];
    const float* v     = (const float*)d_in[1];
    const float* force = (const float*)d_in[2];
    const float* U     = (const float*)d_in[3];
    const float* W     = (const float*)d_in[4];
    const int*   steps = (const int*)d_in[5];

    short* Up = (short*)d_ws;                 // 512 KB
    short* Wp = Up + 32768 * 8;               // 512 KB

    pack_kernel<<<256, 256, 0, stream>>>(U, W, Up, Wp);
    euler_kernel<<<128, 1024, 0, stream>>>(x, v, force,
                                           (const short8*)Up, (const short8*)Wp,
                                           steps, (float*)d_out);
}

// Round 5
// 469.512 us; speedup vs baseline: 1.6482x; 1.6482x over previous
//
#include <hip/hip_runtime.h>
#include <hip/hip_bf16.h>

// EulerIntegrator: B=4096, D=1024, R=256, steps=8, dt=0.01
// Round 5: kill spills BY CONSTRUCTION.
//  - 256 blocks x 1024 threads (16 waves) per 16-row tile: each thread owns
//    16 elements (v_reg[4][4], sv[4][4]) instead of 32. Peak live ~100 regs.
//  - GEMM1: each wave owns ONE 16x16 P-tile (acc=8 regs, 2 accs for ILP).
//    GEMM2: each wave owns FOUR G-tiles (acc=16 regs), 2-deep B double-buffer.
//  - LDS 82.7 KB (> 80 KB) pins 1 block/CU -> 4 waves/SIMD -> 128-reg cap.
//  - Up/Wp packed [nt][kt][lane]: each wave's B-stream is contiguous.
//  - lgkm-only barriers + cross-phase prefetch (loads survive barriers).

#define BB 4096
#define DD 1024
#define RR 256
#define DT 0.01f

typedef __attribute__((ext_vector_type(8))) short short8;   // 8 bf16 = 4 VGPRs
typedef __attribute__((ext_vector_type(4))) float floatx4;  // MFMA acc

// s_waitcnt imm: vmcnt[3:0]|[15:14], expcnt[6:4], lgkmcnt[11:8]
// lgkmcnt(0) only; in-flight global loads survive the barrier.
#define BARRIER_LGKM() do { \
    __builtin_amdgcn_s_waitcnt(0xC07F); \
    __builtin_amdgcn_s_barrier(); \
} while (0)

static __device__ inline unsigned short f2bf(float f) {
    union { float f; unsigned int u; } c; c.f = f;
    unsigned int u = c.u;
    u += 0x7fffu + ((u >> 16) & 1u);   // round-to-nearest-even
    return (unsigned short)(u >> 16);
}
static __device__ inline float bf2f(unsigned short u) {
    union { unsigned int u; float f; } c; c.u = ((unsigned int)u) << 16;
    return c.f;
}

// Pack U [1024][256] and W [256][1024] (fp32 row-major) into bf16 MFMA
// B-fragment order, n-tile-major so each wave streams contiguously:
//   Up[(nt*32 + kt)*64 + lane][j] = U[kt*32 + (lane>>4)*8 + j][nt*16 + (lane&15)]
//   Wp[(nt*8  + kt)*64 + lane][j] = W[kt*32 + (lane>>4)*8 + j][nt*16 + (lane&15)]
__global__ void pack_kernel(const float* __restrict__ U, const float* __restrict__ W,
                            short* __restrict__ Up, short* __restrict__ Wp) {
    int t = blockIdx.x * blockDim.x + threadIdx.x;  // 0..65535
    if (t < 32768) {
        int lane = t & 63;
        int nl = lane & 15, kq = lane >> 4;
        int idx = t >> 6;            // kt*16 + nt
        int nt = idx & 15, kt = idx >> 4;
        short8 o;
#pragma unroll
        for (int j = 0; j < 8; j++) {
            int k = kt * 32 + kq * 8 + j;
            int n = nt * 16 + nl;
            o[j] = (short)f2bf(U[k * RR + n]);
        }
        ((short8*)Up)[(nt * 32 + kt) * 64 + lane] = o;
    } else {
        int t2 = t - 32768;
        int lane = t2 & 63;
        int nl = lane & 15, kq = lane >> 4;
        int idx = t2 >> 6;           // kt*64 + nt
        int nt = idx & 63, kt = idx >> 6;
        short8 o;
#pragma unroll
        for (int j = 0; j < 8; j++) {
            int k = kt * 32 + kq * 8 + j;
            int n = nt * 16 + nl;
            o[j] = (short)f2bf(W[k * DD + n]);
        }
        ((short8*)Wp)[(nt * 8 + kt) * 64 + lane] = o;
    }
}

__global__ __launch_bounds__(1024, 1)
void euler_kernel(const float* __restrict__ x0,
                  const float* __restrict__ v0,
                  const float* __restrict__ force,
                  const short8* __restrict__ Up,
                  const short8* __restrict__ Wp,
                  const int* __restrict__ steps_p,
                  float* __restrict__ out) {
    __shared__ __align__(16) short v_lds[16][1032];   // 33,024 B bf16 v
    __shared__ __align__(16) short f_lds[16][1032];   // 33,024 B bf16 force
    __shared__ __align__(16) short p2_lds[16][520];   // 16,640 B bf16 p^2
    // total 82,688 B > 80 KB -> exactly 1 block/CU (keeps VGPR cap at 128)

    const int tid  = threadIdx.x;
    const int wave = tid >> 6;          // 0..15
    const int lane = tid & 63;
    const int nl   = lane & 15;
    const int quad = lane >> 4;
    const int row0 = blockIdx.x * 16;

    const int steps = steps_p[0];

    // Ownership (GEMM2 C/D layout, 4 tiles/wave):
    //   (j 0..3, r 0..3): row = 4*quad + r, col = 64*wave + 16*j + nl
    float v_reg[4][4], sv[4][4];

#pragma unroll
    for (int j = 0; j < 4; j++) {
        int col = 64 * wave + 16 * j + nl;
#pragma unroll
        for (int r = 0; r < 4; r++) {
            int row = 4 * quad + r;
            long g = (long)(row0 + row) * DD + col;
            float vv = __builtin_nontemporal_load(&v0[g]);
            float ff = __builtin_nontemporal_load(&force[g]);
            v_reg[j][r] = vv;
            sv[j][r] = 0.0f;
            v_lds[row][col] = (short)f2bf(vv);
            f_lds[row][col] = (short)f2bf(ff);
        }
    }

    // GEMM1 B-ring, depth 4 (16 regs). Wave w owns U n-tile w (contiguous 32KB).
    short8 b0r[4];
#pragma unroll
    for (int i = 0; i < 4; i++)
        b0r[i] = Up[(wave * 32 + i) * 64 + lane];

    BARRIER_LGKM();

    for (int s = 0; s < steps; s++) {
        // ---------------- GEMM1: P[16x256] = v @ U ; wave -> n-tile = wave
        floatx4 acc0 = {0.f, 0.f, 0.f, 0.f};
        floatx4 acc1 = {0.f, 0.f, 0.f, 0.f};
#pragma unroll
        for (int kt = 0; kt < 32; kt++) {
            short8 a = *(const short8*)&v_lds[nl][kt * 32 + quad * 8];
            if (kt & 1)
                acc1 = __builtin_amdgcn_mfma_f32_16x16x32_bf16(a, b0r[kt & 3], acc1, 0, 0, 0);
            else
                acc0 = __builtin_amdgcn_mfma_f32_16x16x32_bf16(a, b0r[kt & 3], acc0, 0, 0, 0);
            if (kt < 28)
                b0r[kt & 3] = Up[(wave * 32 + kt + 4) * 64 + lane];
        }

        // GEMM2 kt=0 prologue — in flight across the p2 barrier.
        short8 br[2][4];
#pragma unroll
        for (int j = 0; j < 4; j++)
            br[0][j] = Wp[((4 * wave + j) * 8) * 64 + lane];

        // p^2 epilogue -> LDS (D layout: row = 4*quad + r, col = 16*wave + nl)
#pragma unroll
        for (int r = 0; r < 4; r++) {
            float p = acc0[r] + acc1[r];
            p2_lds[4 * quad + r][16 * wave + nl] = (short)f2bf(p * p);
        }
        BARRIER_LGKM();

        // ---------------- GEMM2: G tiles nt = 4*wave + j, j=0..3
        floatx4 acc[4];
#pragma unroll
        for (int j = 0; j < 4; j++) acc[j] = (floatx4){0.f, 0.f, 0.f, 0.f};
#pragma unroll
        for (int kt = 0; kt < 8; kt++) {
            int cur = kt & 1;
            if (kt < 7) {
#pragma unroll
                for (int j = 0; j < 4; j++)
                    br[cur ^ 1][j] = Wp[((4 * wave + j) * 8 + kt + 1) * 64 + lane];
            }
            short8 a2 = *(const short8*)&p2_lds[nl][kt * 32 + quad * 8];
#pragma unroll
            for (int j = 0; j < 4; j++)
                acc[j] = __builtin_amdgcn_mfma_f32_16x16x32_bf16(a2, br[cur][j], acc[j], 0, 0, 0);
        }

        // next-step GEMM1 prologue — in flight across the end-of-step barrier.
#pragma unroll
        for (int i = 0; i < 4; i++)
            b0r[i] = Up[(wave * 32 + i) * 64 + lane];

        // Euler update epilogue, refresh bf16 v in LDS
#pragma unroll
        for (int j = 0; j < 4; j++) {
            int col = 64 * wave + 16 * j + nl;
#pragma unroll
            for (int r = 0; r < 4; r++) {
                int row = 4 * quad + r;
                float fv = bf2f((unsigned short)f_lds[row][col]);
                sv[j][r] += v_reg[j][r];                 // x accumulates pre-update v
                v_reg[j][r] += DT * (fv - acc[j][r]);
                v_lds[row][col] = (short)f2bf(v_reg[j][r]);
            }
        }
        BARRIER_LGKM();
    }

    // outputs: [cx | cv], cx = x0 + dt * sum(v_t)
#pragma unroll
    for (int j = 0; j < 4; j++) {
        int col = 64 * wave + 16 * j + nl;
#pragma unroll
        for (int r = 0; r < 4; r++) {
            int row = 4 * quad + r;
            long g = (long)(row0 + row) * DD + col;
            float xx = __builtin_nontemporal_load(&x0[g]);
            __builtin_nontemporal_store(xx + DT * sv[j][r], &out[g]);
            __builtin_nontemporal_store(v_reg[j][r], &out[(long)BB * DD + g]);
        }
    }
}

extern "C" void kernel_launch(void* const* d_in, const int* in_sizes, int n_in,
                              void* d_out, int out_size, void* d_ws, size_t ws_size,
                              hipStream_t stream) {
    const float* x     = (const float*)d_in[0];
    const float* v     = (const float*)d_in[1];
    const float* force = (const float*)d_in[2];
    const float* U     = (const float*)d_in[3];
    const float* W     = (const float*)d_in[4];
    const int*   steps = (const int*)d_in[5];

    short* Up = (short*)d_ws;                 // 512 KB
    short* Wp = Up + 32768 * 8;               // 512 KB

    pack_kernel<<<256, 256, 0, stream>>>(U, W, Up, Wp);
    euler_kernel<<<256, 1024, 0, stream>>>(x, v, force,
                                           (const short8*)Up, (const short8*)Wp,
                                           steps, (float*)d_out);
}

// Round 6
// 462.673 us; speedup vs baseline: 1.6726x; 1.0148x over previous
//
#include <hip/hip_runtime.h>
#include <hip/hip_bf16.h>

// EulerIntegrator: B=4096, D=1024, R=256, steps=8, dt=0.01
// Round 6: spill-free with MARGIN.
//  - 256 blocks x 512 threads (8 waves) x 16 rows. Observed allocator cap for
//    512-thr blocks is 128 VGPR (rounds 1-3); we need ~86.
//  - Per-thread persistent state = v_reg[8][4] ONLY (32 regs).
//    sv -> fp32 LDS, force -> bf16 LDS, GEMM2 chunked 2x4 tiles (acc=16).
//  - LDS 140 KB -> 1 block/CU. lgkm-only barriers + cross-phase prefetch.
//  - Spills gone => scratch no longer thrashes per-XCD L2 => Up/Wp (1 MB)
//    stays L2-resident => 2 GB B-stream served at L2 BW (floor ~59 us).

#define BB 4096
#define DD 1024
#define RR 256
#define DT 0.01f

typedef __attribute__((ext_vector_type(8))) short short8;   // 8 bf16 = 4 VGPRs
typedef __attribute__((ext_vector_type(4))) float floatx4;  // MFMA acc

// s_waitcnt imm: vmcnt[3:0]|[15:14], expcnt[6:4], lgkmcnt[11:8]
// lgkmcnt(0) only; in-flight global loads survive the barrier.
#define BARRIER_LGKM() do { \
    __builtin_amdgcn_s_waitcnt(0xC07F); \
    __builtin_amdgcn_s_barrier(); \
} while (0)

static __device__ inline unsigned short f2bf(float f) {
    union { float f; unsigned int u; } c; c.f = f;
    unsigned int u = c.u;
    u += 0x7fffu + ((u >> 16) & 1u);   // round-to-nearest-even
    return (unsigned short)(u >> 16);
}
static __device__ inline float bf2f(unsigned short u) {
    union { unsigned int u; float f; } c; c.u = ((unsigned int)u) << 16;
    return c.f;
}

// Pack U [1024][256] and W [256][1024] (fp32 row-major) into bf16 MFMA
// B-fragment order, n-tile-major so each wave streams contiguously:
//   Up[(nt*32 + kt)*64 + lane][j] = U[kt*32 + (lane>>4)*8 + j][nt*16 + (lane&15)]
//   Wp[(nt*8  + kt)*64 + lane][j] = W[kt*32 + (lane>>4)*8 + j][nt*16 + (lane&15)]
__global__ void pack_kernel(const float* __restrict__ U, const float* __restrict__ W,
                            short* __restrict__ Up, short* __restrict__ Wp) {
    int t = blockIdx.x * blockDim.x + threadIdx.x;  // 0..65535
    if (t < 32768) {
        int lane = t & 63;
        int nl = lane & 15, kq = lane >> 4;
        int idx = t >> 6;            // kt*16 + nt
        int nt = idx & 15, kt = idx >> 4;
        short8 o;
#pragma unroll
        for (int j = 0; j < 8; j++) {
            int k = kt * 32 + kq * 8 + j;
            int n = nt * 16 + nl;
            o[j] = (short)f2bf(U[k * RR + n]);
        }
        ((short8*)Up)[(nt * 32 + kt) * 64 + lane] = o;
    } else {
        int t2 = t - 32768;
        int lane = t2 & 63;
        int nl = lane & 15, kq = lane >> 4;
        int idx = t2 >> 6;           // kt*64 + nt
        int nt = idx & 63, kt = idx >> 6;
        short8 o;
#pragma unroll
        for (int j = 0; j < 8; j++) {
            int k = kt * 32 + kq * 8 + j;
            int n = nt * 16 + nl;
            o[j] = (short)f2bf(W[k * DD + n]);
        }
        ((short8*)Wp)[(nt * 8 + kt) * 64 + lane] = o;
    }
}

__global__ __launch_bounds__(512, 1)
void euler_kernel(const float* __restrict__ x0,
                  const float* __restrict__ v0,
                  const float* __restrict__ force,
                  const short8* __restrict__ Up,
                  const short8* __restrict__ Wp,
                  const int* __restrict__ steps_p,
                  float* __restrict__ out) {
    __shared__ __align__(16) short vb_lds[16][1032];   // 33,024 B bf16 v
    __shared__ __align__(16) short fb_lds[16][1032];   // 33,024 B bf16 force
    __shared__ __align__(16) float sv_lds[16][1028];   // 65,792 B fp32 sum(v)
    __shared__ __align__(16) short p2_lds[16][264];    //  8,448 B bf16 p^2
    // total 140,288 B -> 1 block/CU

    const int tid  = threadIdx.x;
    const int wave = tid >> 6;          // 0..7
    const int lane = tid & 63;
    const int nl   = lane & 15;
    const int quad = lane >> 4;
    const int row0 = blockIdx.x * 16;

    const int steps = steps_p[0];

    // Ownership (GEMM2 C/D layout, 8 tiles/wave in 2 chunks):
    //   (tt 0..7, r 0..3): row = 4*quad + r, col = 128*wave + 16*tt + nl
    float v_reg[8][4];

#pragma unroll
    for (int tt = 0; tt < 8; tt++) {
        int col = 128 * wave + 16 * tt + nl;
#pragma unroll
        for (int r = 0; r < 4; r++) {
            int row = 4 * quad + r;
            long g = (long)(row0 + row) * DD + col;
            float vv = __builtin_nontemporal_load(&v0[g]);
            float ff = __builtin_nontemporal_load(&force[g]);
            v_reg[tt][r] = vv;
            vb_lds[row][col] = (short)f2bf(vv);
            fb_lds[row][col] = (short)f2bf(ff);
            sv_lds[row][col] = 0.0f;
        }
    }

    // GEMM1 B-rings, depth 4 (32 regs). Wave w owns U n-tiles 2w, 2w+1.
    short8 b0r[4], b1r[4];
#pragma unroll
    for (int i = 0; i < 4; i++) {
        b0r[i] = Up[((2 * wave    ) * 32 + i) * 64 + lane];
        b1r[i] = Up[((2 * wave + 1) * 32 + i) * 64 + lane];
    }

    BARRIER_LGKM();

    for (int s = 0; s < steps; s++) {
        // ---------------- GEMM1: P[16x256] = v @ U ; n-tiles 2w, 2w+1
        floatx4 acc0 = {0.f, 0.f, 0.f, 0.f};
        floatx4 acc1 = {0.f, 0.f, 0.f, 0.f};
#pragma unroll
        for (int kt = 0; kt < 32; kt++) {
            short8 a = *(const short8*)&vb_lds[nl][kt * 32 + quad * 8];
            acc0 = __builtin_amdgcn_mfma_f32_16x16x32_bf16(a, b0r[kt & 3], acc0, 0, 0, 0);
            acc1 = __builtin_amdgcn_mfma_f32_16x16x32_bf16(a, b1r[kt & 3], acc1, 0, 0, 0);
            if (kt < 28) {
                b0r[kt & 3] = Up[((2 * wave    ) * 32 + kt + 4) * 64 + lane];
                b1r[kt & 3] = Up[((2 * wave + 1) * 32 + kt + 4) * 64 + lane];
            }
        }

        // GEMM2 chunk-A prologue (kt=0, tiles 8w..8w+3) — crosses the barrier.
        short8 br[2][4];
#pragma unroll
        for (int j = 0; j < 4; j++)
            br[0][j] = Wp[((8 * wave + j) * 8) * 64 + lane];

        // p^2 epilogue -> LDS (cols 32w..32w+31)
#pragma unroll
        for (int r = 0; r < 4; r++) {
            int prow = 4 * quad + r;
            float p0 = acc0[r], p1 = acc1[r];
            p2_lds[prow][32 * wave + nl]      = (short)f2bf(p0 * p0);
            p2_lds[prow][32 * wave + 16 + nl] = (short)f2bf(p1 * p1);
        }
        BARRIER_LGKM();

        // ---------------- GEMM2 chunk A: tiles tt=0..3 (nt = 8w+j)
        floatx4 acc[4];
#pragma unroll
        for (int j = 0; j < 4; j++) acc[j] = (floatx4){0.f, 0.f, 0.f, 0.f};
#pragma unroll
        for (int kt = 0; kt < 8; kt++) {
            int cur = kt & 1;
            if (kt < 7) {
#pragma unroll
                for (int j = 0; j < 4; j++)
                    br[cur ^ 1][j] = Wp[((8 * wave + j) * 8 + kt + 1) * 64 + lane];
            }
            short8 a2 = *(const short8*)&p2_lds[nl][kt * 32 + quad * 8];
#pragma unroll
            for (int j = 0; j < 4; j++)
                acc[j] = __builtin_amdgcn_mfma_f32_16x16x32_bf16(a2, br[cur][j], acc[j], 0, 0, 0);
        }

        // chunk-B prologue (kt=0, tiles 8w+4..8w+7) — br slot 0 is dead after
        // the last chunk-A MFMAs consume it; compiler reuses regs.
        short8 brB0[4];
#pragma unroll
        for (int j = 0; j < 4; j++)
            brB0[j] = Wp[((8 * wave + 4 + j) * 8) * 64 + lane];

        // epilogue A: Euler update for tt=0..3
#pragma unroll
        for (int tt = 0; tt < 4; tt++) {
            int col = 128 * wave + 16 * tt + nl;
#pragma unroll
            for (int r = 0; r < 4; r++) {
                int row = 4 * quad + r;
                float fv = bf2f((unsigned short)fb_lds[row][col]);
                sv_lds[row][col] += v_reg[tt][r];        // pre-update v
                v_reg[tt][r] += DT * (fv - acc[tt][r]);
                vb_lds[row][col] = (short)f2bf(v_reg[tt][r]);
            }
        }

        // ---------------- GEMM2 chunk B: tiles tt=4..7 (nt = 8w+4+j)
#pragma unroll
        for (int j = 0; j < 4; j++) acc[j] = (floatx4){0.f, 0.f, 0.f, 0.f};
        br[0][0] = brB0[0]; br[0][1] = brB0[1]; br[0][2] = brB0[2]; br[0][3] = brB0[3];
#pragma unroll
        for (int kt = 0; kt < 8; kt++) {
            int cur = kt & 1;
            if (kt < 7) {
#pragma unroll
                for (int j = 0; j < 4; j++)
                    br[cur ^ 1][j] = Wp[((8 * wave + 4 + j) * 8 + kt + 1) * 64 + lane];
            }
            short8 a2 = *(const short8*)&p2_lds[nl][kt * 32 + quad * 8];
#pragma unroll
            for (int j = 0; j < 4; j++)
                acc[j] = __builtin_amdgcn_mfma_f32_16x16x32_bf16(a2, br[cur][j], acc[j], 0, 0, 0);
        }

        // next-step GEMM1 prologue — crosses the end-of-step barrier.
#pragma unroll
        for (int i = 0; i < 4; i++) {
            b0r[i] = Up[((2 * wave    ) * 32 + i) * 64 + lane];
            b1r[i] = Up[((2 * wave + 1) * 32 + i) * 64 + lane];
        }

        // epilogue B: Euler update for tt=4..7
#pragma unroll
        for (int j = 0; j < 4; j++) {
            int tt = 4 + j;
            int col = 128 * wave + 16 * tt + nl;
#pragma unroll
            for (int r = 0; r < 4; r++) {
                int row = 4 * quad + r;
                float fv = bf2f((unsigned short)fb_lds[row][col]);
                sv_lds[row][col] += v_reg[tt][r];
                v_reg[tt][r] += DT * (fv - acc[j][r]);
                vb_lds[row][col] = (short)f2bf(v_reg[tt][r]);
            }
        }
        BARRIER_LGKM();
    }

    // outputs: [cx | cv], cx = x0 + dt * sum(v_t)
#pragma unroll
    for (int tt = 0; tt < 8; tt++) {
        int col = 128 * wave + 16 * tt + nl;
#pragma unroll
        for (int r = 0; r < 4; r++) {
            int row = 4 * quad + r;
            long g = (long)(row0 + row) * DD + col;
            float xx = __builtin_nontemporal_load(&x0[g]);
            __builtin_nontemporal_store(xx + DT * sv_lds[row][col], &out[g]);
            __builtin_nontemporal_store(v_reg[tt][r], &out[(long)BB * DD + g]);
        }
    }
}

extern "C" void kernel_launch(void* const* d_in, const int* in_sizes, int n_in,
                              void* d_out, int out_size, void* d_ws, size_t ws_size,
                              hipStream_t stream) {
    const float* x     = (const float*)d_in[0];
    const float* v     = (const float*)d_in[1];
    const float* force = (const float*)d_in[2];
    const float* U     = (const float*)d_in[3];
    const float* W     = (const float*)d_in[4];
    const int*   steps = (const int*)d_in[5];

    short* Up = (short*)d_ws;                 // 512 KB
    short* Wp = Up + 32768 * 8;               // 512 KB

    pack_kernel<<<256, 256, 0, stream>>>(U, W, Up, Wp);
    euler_kernel<<<256, 512, 0, stream>>>(x, v, force,
                                          (const short8*)Up, (const short8*)Wp,
                                          steps, (float*)d_out);
}